// Round 2
// baseline (2606.088 us; speedup 1.0000x reference)
//
#include <hip/hip_runtime.h>

// GaussianSamplingPredict: B=1024, C=100, S=1000
//   scaled_cov = cov + 1e-6 I  (DECODING_TIME = 1.0)
//   L = cholesky(scaled_cov)                    [B,C,C]
//   t[b,s,d] = u[b,d] + sum_c z[s,c] * L[b,d,c]
//   out[b,d] = mean_s softmax_d(t[b,s,:])[d]
//
// One block per batch b. Fully fused. R1 change: 2-row (not 4-row) register
// tile in Phase D -> live set ~105 VGPR, no scratch spill (R0 spilled 2.1 GB
// to scratch and was scratch-BW-bound at 1.39 ms).

#define CC   100
#define SS   1000
#define PCH  101     // Cholesky-phase LDS stride (odd -> conflict-free rows)
#define PMM  104     // matmul-phase stride (mult of 4 -> 16B-aligned float4)
#define EPSF 1e-6f

__global__ __launch_bounds__(256, 3)
void gsp_kernel(const float* __restrict__ u,
                const float* __restrict__ cov,
                const float* __restrict__ z,
                float* __restrict__ out, int B) {
    // 100*104*4 = 41.6 KB main buffer (Cholesky uses first 100*101 floats)
    __shared__ alignas(16) float LS[CC * PMM];
    __shared__ float ush[CC];
    __shared__ float outWv[4 * CC];

    const int tid = threadIdx.x;
    const int b   = blockIdx.x;

    // ---- Phase A: load cov (+eps I) into stride-101 storage ----
    for (int idx = tid; idx < CC * CC; idx += 256) {
        const int r = idx / CC;
        const int c = idx - r * CC;
        float v = cov[(size_t)b * (CC * CC) + idx];
        if (r == c) v += EPSF;
        LS[r * PCH + c] = v;
    }
    if (tid < CC) ush[tid] = u[(size_t)b * CC + tid];
    __syncthreads();

    // ---- Phase B: Cholesky, transposed storage: LS[x*PCH+y] = L[y][x], y>=x ----
    {
        const int tx = tid & 63;
        const int ty = tid >> 6;
        for (int j = 0; j < CC; ++j) {
            if (tid == 0) LS[j * PCH + j] = sqrtf(LS[j * PCH + j]);
            __syncthreads();
            const float dinv = 1.0f / LS[j * PCH + j];
            for (int i = j + 1 + tid; i < CC; i += 256)
                LS[j * PCH + i] *= dinv;          // row access: conflict-free
            __syncthreads();
            // rank-1 trailing update: M[k][i] -= M[j][i]*M[j][k], j<k<=i
            for (int k = j + 1 + ty; k < CC; k += 4) {
                const float lkj = LS[j * PCH + k];      // broadcast
                for (int i = k + tx; i < CC; i += 64)
                    LS[k * PCH + i] -= LS[j * PCH + i] * lkj;  // row access
            }
            __syncthreads();
        }
    }

    // ---- Phase C: repack to row-major L[d][c] (stride PMM), zero c>d ----
    {
        float tmp[41];
        #pragma unroll
        for (int t = 0; t < 41; ++t) {
            const int idx = tid + t * 256;
            float v = 0.0f;
            if (idx < CC * PMM) {
                const int d = idx / PMM;
                const int c = idx - d * PMM;
                if (c <= d) v = LS[c * PCH + d];   // M[c][d] = L[d][c]
            }
            tmp[t] = v;
        }
        __syncthreads();
        #pragma unroll
        for (int t = 0; t < 41; ++t) {
            const int idx = tid + t * 256;
            if (idx < CC * PMM) LS[idx] = tmp[t];
        }
        __syncthreads();
    }

    // ---- Phase D: matmul + softmax + mean ----
    // 4-lane group: lane q = tid&3 owns d in [25q, 25q+25); group g = tid>>2
    // owns 2 consecutive s-rows per pass. 8 passes of 128 rows cover S=1000
    // (tail masked). Per-(dd,cb) the wave reads only 4 distinct LDS float4s
    // (disjoint banks) -> broadcast, conflict-free.
    const int q = tid & 3;
    const int g = tid >> 2;
    const float4* __restrict__ z4 = reinterpret_cast<const float4*>(z);

    float regAcc[25];
    #pragma unroll
    for (int dd = 0; dd < 25; ++dd) regAcc[dd] = 0.0f;

    for (int pass = 0; pass < 8; ++pass) {
        const int s0 = pass * 128 + g * 2;
        const int r0 = (s0 + 0 < SS) ? s0 + 0 : SS - 1;
        const int r1 = (s0 + 1 < SS) ? s0 + 1 : SS - 1;

        float acc[2][25];
        #pragma unroll
        for (int r = 0; r < 2; ++r)
            #pragma unroll
            for (int dd = 0; dd < 25; ++dd) acc[r][dd] = 0.0f;

        for (int cb = 0; cb < 25; ++cb) {
            const float4 z0 = z4[r0 * 25 + cb];
            const float4 z1 = z4[r1 * 25 + cb];
            #pragma unroll
            for (int dd = 0; dd < 25; ++dd) {
                const float4 lv =
                    *reinterpret_cast<const float4*>(&LS[(q * 25 + dd) * PMM + cb * 4]);
                acc[0][dd] += z0.x * lv.x + z0.y * lv.y + z0.z * lv.z + z0.w * lv.w;
                acc[1][dd] += z1.x * lv.x + z1.y * lv.y + z1.z * lv.z + z1.w * lv.w;
            }
        }

        // add u
        #pragma unroll
        for (int dd = 0; dd < 25; ++dd) {
            const float uv = ush[q * 25 + dd];
            acc[0][dd] += uv;
            acc[1][dd] += uv;
        }

        // softmax per row (100 classes split across the 4-lane group) + mean acc
        #pragma unroll
        for (int r = 0; r < 2; ++r) {
            float m = acc[r][0];
            #pragma unroll
            for (int dd = 1; dd < 25; ++dd) m = fmaxf(m, acc[r][dd]);
            m = fmaxf(m, __shfl_xor(m, 1));
            m = fmaxf(m, __shfl_xor(m, 2));
            float sum = 0.0f;
            #pragma unroll
            for (int dd = 0; dd < 25; ++dd) {
                const float e = __expf(acc[r][dd] - m);
                acc[r][dd] = e;
                sum += e;
            }
            sum += __shfl_xor(sum, 1);
            sum += __shfl_xor(sum, 2);
            const float w = (s0 + r < SS) ? (1.0f / sum) : 0.0f;
            #pragma unroll
            for (int dd = 0; dd < 25; ++dd) regAcc[dd] += acc[r][dd] * w;
        }
    }

    // ---- reduce: lanes with same q within wave (xor 4,8,16,32), then waves ----
    #pragma unroll
    for (int dd = 0; dd < 25; ++dd) {
        float v = regAcc[dd];
        v += __shfl_xor(v, 4);
        v += __shfl_xor(v, 8);
        v += __shfl_xor(v, 16);
        v += __shfl_xor(v, 32);
        regAcc[dd] = v;
    }
    const int lane = tid & 63;
    const int wv   = tid >> 6;
    if (lane < 4) {
        #pragma unroll
        for (int dd = 0; dd < 25; ++dd)
            outWv[wv * CC + lane * 25 + dd] = regAcc[dd];
    }
    __syncthreads();
    for (int d = tid; d < CC; d += 256) {
        out[(size_t)b * CC + d] =
            (outWv[d] + outWv[CC + d] + outWv[2 * CC + d] + outWv[3 * CC + d]) *
            (1.0f / (float)SS);
    }
}

extern "C" void kernel_launch(void* const* d_in, const int* in_sizes, int n_in,
                              void* d_out, int out_size, void* d_ws, size_t ws_size,
                              hipStream_t stream) {
    const float* u   = (const float*)d_in[0];
    const float* cov = (const float*)d_in[1];
    const float* z   = (const float*)d_in[2];
    float* out = (float*)d_out;
    const int B = in_sizes[0] / CC;   // 1024
    gsp_kernel<<<dim3(B), dim3(256), 0, stream>>>(u, cov, z, out, B);
}

// Round 3
// 1095.485 us; speedup vs baseline: 2.3789x; 2.3789x over previous
//
#include <hip/hip_runtime.h>

// GaussianSamplingPredict: B=1024, C=100, S=1000
//   L = cholesky(cov + 1e-6 I)                  [B,C,C]
//   t[b,s,d] = u[b,d] + sum_c z[s,c] * L[b,d,c]
//   out[b,d] = mean_s softmax_d(t[b,s,:])[d]
//
// R2: two kernels.
//  K1 chol_kernel: 1 wave/block, wave-synchronous right-looking Cholesky in
//     LDS (stride-100, row accesses only -> conflict-free), 1 sync per
//     column. Writes row-major L[d][c] (upper zeroed) to d_ws.
//  K2 pred_kernel: stages L into LDS (stride 104 for aligned float4 reads),
//     then 4-lane-group register-tiled matmul + softmax + mean.
//     __launch_bounds__(256,2): empirically VGPR cap = 256/n = 128; live set
//     ~95 floats -> NO scratch spill (R0/R1 were scratch-BW-bound).

#define CC   100
#define SS   1000
#define PMM  104
#define EPSF 1e-6f

// ---------------- K1: per-batch Cholesky, one wave per block ----------------
__global__ __launch_bounds__(64)
void chol_kernel(const float* __restrict__ cov, float* __restrict__ gL) {
    __shared__ float M[CC * CC];          // M[x*100+y] = L[y][x] (transposed)
    const int lane = threadIdx.x;
    const int b    = blockIdx.x;

    const float4* c4 = reinterpret_cast<const float4*>(cov + (size_t)b * CC * CC);
    for (int t = lane; t < CC * CC / 4; t += 64)
        *reinterpret_cast<float4*>(&M[t * 4]) = c4[t];
    __syncthreads();
    for (int d = lane; d < CC; d += 64) M[d * CC + d] += EPSF;
    __syncthreads();

    for (int j = 0; j < CC; ++j) {
        const float val   = M[j * CC + j];     // raw Schur diag (synced)
        const float s     = sqrtf(val);
        const float dinv  = 1.0f / s;
        const float dinv2 = 1.0f / val;
        // trailing rank-1 update using RAW row j, dinv^2 folded in:
        // M[k][i] -= M[j][i] * (M[j][k] / val)
        for (int k = j + 1; k < CC; ++k) {
            const float t = M[j * CC + k] * dinv2;   // wave-uniform broadcast
            for (int i = k + lane; i < CC; i += 64)
                M[k * CC + i] -= M[j * CC + i] * t;  // consecutive -> no conflict
        }
        // finalize row j -> L values
        for (int i = j + 1 + lane; i < CC; i += 64) M[j * CC + i] *= dinv;
        if (lane == 0) M[j * CC + j] = s;
        __syncthreads();   // single wave: cheap
    }

    // write row-major L[d][c], zero upper triangle; coalesced over idx
    float* outp = gL + (size_t)b * CC * CC;
    for (int idx = lane; idx < CC * CC; idx += 64) {
        const int d = idx / CC, c = idx - d * CC;
        outp[idx] = (c <= d) ? M[c * CC + d] : 0.0f;
    }
}

// ---------------- K2: matmul + softmax + mean ----------------
__global__ __launch_bounds__(256, 2)
void pred_kernel(const float* __restrict__ u,
                 const float* __restrict__ gL,
                 const float* __restrict__ z,
                 float* __restrict__ out) {
    __shared__ alignas(16) float LS[CC * PMM];   // 41.6 KB
    __shared__ float ush[CC];
    __shared__ float outWv[4 * CC];

    const int tid = threadIdx.x;
    const int b   = blockIdx.x;

    // stage L: flat float4 copy global -> LDS (rows are 25 float4s; pad cols
    // 100..103 never read since cb*4+3 <= 99)
    const float4* Lg4 = reinterpret_cast<const float4*>(gL + (size_t)b * CC * CC);
    for (int t4 = tid; t4 < CC * CC / 4; t4 += 256) {
        const int d = t4 / 25, c4i = t4 - d * 25;
        *reinterpret_cast<float4*>(&LS[d * PMM + c4i * 4]) = Lg4[t4];
    }
    if (tid < CC) ush[tid] = u[(size_t)b * CC + tid];
    __syncthreads();

    // 4-lane group: lane q = tid&3 owns d in [25q, 25q+25); group g = tid>>2
    // owns 2 consecutive s-rows per pass; 8 passes cover S=1000 (tail masked).
    // Per (dd,cb) the wave reads 4 distinct LDS float4s -> broadcast.
    const int q = tid & 3;
    const int g = tid >> 2;
    const float4* __restrict__ z4 = reinterpret_cast<const float4*>(z);

    float regAcc[25];
    #pragma unroll
    for (int dd = 0; dd < 25; ++dd) regAcc[dd] = 0.0f;

    for (int pass = 0; pass < 8; ++pass) {
        const int s0 = pass * 128 + g * 2;
        const int r0 = (s0 + 0 < SS) ? s0 + 0 : SS - 1;
        const int r1 = (s0 + 1 < SS) ? s0 + 1 : SS - 1;

        float acc[2][25];
        #pragma unroll
        for (int dd = 0; dd < 25; ++dd) { acc[0][dd] = 0.0f; acc[1][dd] = 0.0f; }

        for (int cb = 0; cb < 25; ++cb) {
            const float4 z0 = z4[r0 * 25 + cb];
            const float4 z1 = z4[r1 * 25 + cb];
            #pragma unroll
            for (int dd = 0; dd < 25; ++dd) {
                const float4 lv =
                    *reinterpret_cast<const float4*>(&LS[(q * 25 + dd) * PMM + cb * 4]);
                acc[0][dd] += z0.x * lv.x + z0.y * lv.y + z0.z * lv.z + z0.w * lv.w;
                acc[1][dd] += z1.x * lv.x + z1.y * lv.y + z1.z * lv.z + z1.w * lv.w;
            }
        }

        #pragma unroll
        for (int dd = 0; dd < 25; ++dd) {
            const float uv = ush[q * 25 + dd];
            acc[0][dd] += uv;
            acc[1][dd] += uv;
        }

        #pragma unroll
        for (int r = 0; r < 2; ++r) {
            float m = acc[r][0];
            #pragma unroll
            for (int dd = 1; dd < 25; ++dd) m = fmaxf(m, acc[r][dd]);
            m = fmaxf(m, __shfl_xor(m, 1));
            m = fmaxf(m, __shfl_xor(m, 2));
            float sum = 0.0f;
            #pragma unroll
            for (int dd = 0; dd < 25; ++dd) {
                const float e = __expf(acc[r][dd] - m);
                acc[r][dd] = e;
                sum += e;
            }
            sum += __shfl_xor(sum, 1);
            sum += __shfl_xor(sum, 2);
            const float w = (s0 + r < SS) ? (1.0f / sum) : 0.0f;
            #pragma unroll
            for (int dd = 0; dd < 25; ++dd) regAcc[dd] += acc[r][dd] * w;
        }
    }

    // reduce across lanes with same q (xor 4,8,16,32), then across waves
    #pragma unroll
    for (int dd = 0; dd < 25; ++dd) {
        float v = regAcc[dd];
        v += __shfl_xor(v, 4);
        v += __shfl_xor(v, 8);
        v += __shfl_xor(v, 16);
        v += __shfl_xor(v, 32);
        regAcc[dd] = v;
    }
    const int lane = tid & 63;
    const int wv   = tid >> 6;
    if (lane < 4) {
        #pragma unroll
        for (int dd = 0; dd < 25; ++dd)
            outWv[wv * CC + lane * 25 + dd] = regAcc[dd];
    }
    __syncthreads();
    for (int d = tid; d < CC; d += 256) {
        out[(size_t)b * CC + d] =
            (outWv[d] + outWv[CC + d] + outWv[2 * CC + d] + outWv[3 * CC + d]) *
            (1.0f / (float)SS);
    }
}

extern "C" void kernel_launch(void* const* d_in, const int* in_sizes, int n_in,
                              void* d_out, int out_size, void* d_ws, size_t ws_size,
                              hipStream_t stream) {
    const float* u   = (const float*)d_in[0];
    const float* cov = (const float*)d_in[1];
    const float* z   = (const float*)d_in[2];
    float* outp = (float*)d_out;
    float* gL   = (float*)d_ws;                  // 1024*100*100*4 = 40.96 MB
    const int B = in_sizes[0] / CC;              // 1024

    chol_kernel<<<dim3(B), dim3(64), 0, stream>>>(cov, gL);
    pred_kernel<<<dim3(B), dim3(256), 0, stream>>>(u, gL, z, outp);
}

// Round 4
// 400.062 us; speedup vs baseline: 6.5142x; 2.7383x over previous
//
#include <hip/hip_runtime.h>

// GaussianSamplingPredict: B=1024, C=100, S=1000
//   L = cholesky(cov + 1e-6 I); t[b,s,d] = u[b,d] + sum_c z[s,c]*L[b,d,c]
//   out[b,d] = mean_s softmax_d(t[b,s,:])[d]
//
// R3:
//  K0 zconv: pack z into MFMA A-frag-ordered bf16 (c padded 100->128, s->1008)
//  K1 chol : wave-synchronous Cholesky with 2-D (4 k-rows x 16 i-cols) lane
//            tiling -> independent k-iterations (R2's serial k-loop was a
//            ~250-cyc dependent LDS chain = 620 us). Epilogue packs L into
//            MFMA B-frag-ordered bf16 (row d, 8 contiguous c per lane).
//  K2 pred : per-block MFMA 16x16x32 bf16. 28 B-frags (L) persist in VGPRs,
//            A-frags stream from L2-resident zb. No LDS in hot loop (R2 was
//            DS-pipe-bound at ~400 us). Softmax via 4 xor-shuffles over the
//            16 lanes holding one s-row.

#define CC   100
#define SS   1000
#define EPSF 1e-6f
#define NDT  7      // d-tiles: 7*16 = 112 >= 100
#define NCS  4      // c-steps: 4*32 = 128 >= 100
#define NST  63     // s-tiles: 63*16 = 1008 >= 1000

typedef short  s8 __attribute__((ext_vector_type(8)));   // 8 bf16 (4 VGPR)
typedef float  f4 __attribute__((ext_vector_type(4)));

__device__ inline unsigned short f2bf(float x) {          // round-nearest-even
    unsigned u = __float_as_uint(x);
    return (unsigned short)((u + 0x7fffu + ((u >> 16) & 1u)) >> 16);
}

// ---------------- K0: pack z -> bf16 A-frags ----------------
// zb frag layout: [stile][cstep][lane][j]; A-frag lane l: s = stile*16+(l&15),
// c = cstep*32 + (l>>4)*8 + j. Zero-pad s>=1000, c>=100.
__global__ __launch_bounds__(256)
void zconv_kernel(const float* __restrict__ z, unsigned short* __restrict__ zb) {
    const int stile = blockIdx.x;            // 0..62
    const int cs = threadIdx.x >> 6;
    const int l  = threadIdx.x & 63;
    const int s  = stile * 16 + (l & 15);
    const int c0 = cs * 32 + (l >> 4) * 8;
    unsigned short v[8];
    #pragma unroll
    for (int j = 0; j < 8; ++j) {
        const int c = c0 + j;
        const float x = (s < SS && c < CC) ? z[(size_t)s * CC + c] : 0.0f;
        v[j] = f2bf(x);
    }
    uint4 pk;
    pk.x = (unsigned)v[0] | ((unsigned)v[1] << 16);
    pk.y = (unsigned)v[2] | ((unsigned)v[3] << 16);
    pk.z = (unsigned)v[4] | ((unsigned)v[5] << 16);
    pk.w = (unsigned)v[6] | ((unsigned)v[7] << 16);
    reinterpret_cast<uint4*>(zb)[(stile * NCS + cs) * 64 + l] = pk;
}

// ---------------- K1: Cholesky + B-frag pack ----------------
__global__ __launch_bounds__(64)
void chol_kernel(const float* __restrict__ cov, unsigned short* __restrict__ Lb) {
    __shared__ float M[CC * CC];      // M[x*100+y] = L[y][x] (transposed)
    const int l  = threadIdx.x;
    const int b  = blockIdx.x;
    const int tx = l & 15;
    const int ty = l >> 4;

    const float4* c4 = reinterpret_cast<const float4*>(cov + (size_t)b * CC * CC);
    for (int t = l; t < CC * CC / 4; t += 64)
        reinterpret_cast<float4*>(M)[t] = c4[t];
    __syncthreads();
    for (int d = l; d < CC; d += 64) M[d * CC + d] += EPSF;
    __syncthreads();

    for (int j = 0; j < CC; ++j) {
        const float val   = M[j * CC + j];
        const float s     = sqrtf(val);
        const float dinv  = 1.0f / s;
        const float dinv2 = 1.0f / val;
        // trailing rank-1 update with raw row j, 2-D lane tiling:
        // ty owns k-rows (stride 4) -> independent iterations (ILP), tx owns
        // i-cols (stride 16, consecutive -> conflict-free-ish)
        for (int k = j + 1 + ty; k < CC; k += 4) {
            const float t = M[j * CC + k] * dinv2;
            for (int i = k + tx; i < CC; i += 16)
                M[k * CC + i] -= M[j * CC + i] * t;
        }
        for (int i = j + 1 + l; i < CC; i += 64) M[j * CC + i] *= dinv;
        if (l == 0) M[j * CC + j] = s;
        __syncthreads();
    }

    // pack B-frags: Lb[b][dt][cs][lane][j]; lane l: d = dt*16+(l&15),
    // c = cs*32+(l>>4)*8+j; val = L[d][c] = M[c*100+d] if c<=d<100 else 0.
    unsigned short* outp = Lb + (size_t)b * (NDT * NCS * 64 * 8);
    for (int f = 0; f < NDT * NCS; ++f) {
        const int dt = f >> 2, cs = f & 3;
        const int d  = dt * 16 + tx;
        const int c0 = cs * 32 + ty * 8;
        unsigned short v[8];
        #pragma unroll
        for (int j = 0; j < 8; ++j) {
            const int c = c0 + j;
            float x = 0.0f;
            if (d < CC && c <= d) x = M[c * CC + d];   // c<=d implies c<100
            v[j] = f2bf(x);
        }
        uint4 pk;
        pk.x = (unsigned)v[0] | ((unsigned)v[1] << 16);
        pk.y = (unsigned)v[2] | ((unsigned)v[3] << 16);
        pk.z = (unsigned)v[4] | ((unsigned)v[5] << 16);
        pk.w = (unsigned)v[6] | ((unsigned)v[7] << 16);
        reinterpret_cast<uint4*>(outp)[f * 64 + l] = pk;
    }
}

// ---------------- K2: MFMA matmul + softmax + mean ----------------
__global__ __launch_bounds__(256, 1)
void pred_kernel(const float* __restrict__ u,
                 const unsigned short* __restrict__ Lb,
                 const unsigned short* __restrict__ zb,
                 float* __restrict__ out) {
    __shared__ float red[4 * NDT * 16];
    const int tid = threadIdx.x, b = blockIdx.x;
    const int w  = tid >> 6;
    const int l  = tid & 63;
    const int li = l & 15;
    const int hi = l >> 4;

    // persistent B-frags (L): 28 x 4 VGPR = 112 VGPR
    s8 Bf[NDT][NCS];
    const s8* Lb8 = reinterpret_cast<const s8*>(Lb + (size_t)b * (NDT * NCS * 64 * 8));
    #pragma unroll
    for (int dt = 0; dt < NDT; ++dt)
        #pragma unroll
        for (int cs = 0; cs < NCS; ++cs)
            Bf[dt][cs] = Lb8[(dt * NCS + cs) * 64 + l];

    float ureg[NDT];
    #pragma unroll
    for (int dt = 0; dt < NDT; ++dt) {
        const int d = dt * 16 + li;
        ureg[dt] = (d < CC) ? u[(size_t)b * CC + d] : 0.0f;
    }

    float meanAcc[NDT];
    #pragma unroll
    for (int dt = 0; dt < NDT; ++dt) meanAcc[dt] = 0.0f;

    const s8* zb8 = reinterpret_cast<const s8*>(zb);

    for (int st = w; st < NST; st += 4) {
        s8 Af[NCS];
        #pragma unroll
        for (int cs = 0; cs < NCS; ++cs)
            Af[cs] = zb8[(st * NCS + cs) * 64 + l];

        f4 acc[NDT];
        #pragma unroll
        for (int dt = 0; dt < NDT; ++dt) acc[dt] = (f4){0.f, 0.f, 0.f, 0.f};

        #pragma unroll
        for (int cs = 0; cs < NCS; ++cs)
            #pragma unroll
            for (int dt = 0; dt < NDT; ++dt)
                acc[dt] = __builtin_amdgcn_mfma_f32_16x16x32_bf16(
                              Af[cs], Bf[dt][cs], acc[dt], 0, 0, 0);

        // D layout: col(d_local)=li, row(s_local)=hi*4+r
        #pragma unroll
        for (int r = 0; r < 4; ++r) {
            const int s = st * 16 + hi * 4 + r;
            float tv[NDT];
            #pragma unroll
            for (int dt = 0; dt < NDT; ++dt) {
                float x = acc[dt][r] + ureg[dt];
                if (dt == NDT - 1 && li >= 4) x = -1e30f;   // pad d >= 100
                tv[dt] = x;
            }
            float m = tv[0];
            #pragma unroll
            for (int dt = 1; dt < NDT; ++dt) m = fmaxf(m, tv[dt]);
            m = fmaxf(m, __shfl_xor(m, 1));
            m = fmaxf(m, __shfl_xor(m, 2));
            m = fmaxf(m, __shfl_xor(m, 4));
            m = fmaxf(m, __shfl_xor(m, 8));
            float e[NDT], sum = 0.0f;
            #pragma unroll
            for (int dt = 0; dt < NDT; ++dt) {
                e[dt] = __expf(tv[dt] - m);
                sum += e[dt];
            }
            sum += __shfl_xor(sum, 1);
            sum += __shfl_xor(sum, 2);
            sum += __shfl_xor(sum, 4);
            sum += __shfl_xor(sum, 8);
            const float wt = (s < SS) ? 1.0f / sum : 0.0f;
            #pragma unroll
            for (int dt = 0; dt < NDT; ++dt) meanAcc[dt] += e[dt] * wt;
        }
    }

    // sum the 4 hi-groups (same d, different s-rows)
    #pragma unroll
    for (int dt = 0; dt < NDT; ++dt) {
        float v = meanAcc[dt];
        v += __shfl_xor(v, 16);
        v += __shfl_xor(v, 32);
        meanAcc[dt] = v;
    }
    if (l < 16) {
        #pragma unroll
        for (int dt = 0; dt < NDT; ++dt)
            red[(w * NDT + dt) * 16 + l] = meanAcc[dt];
    }
    __syncthreads();
    if (tid < CC) {
        const int dt = tid >> 4, li2 = tid & 15;
        const float sum = red[(0 * NDT + dt) * 16 + li2]
                        + red[(1 * NDT + dt) * 16 + li2]
                        + red[(2 * NDT + dt) * 16 + li2]
                        + red[(3 * NDT + dt) * 16 + li2];
        out[(size_t)b * CC + tid] = sum * (1.0f / (float)SS);
    }
}

extern "C" void kernel_launch(void* const* d_in, const int* in_sizes, int n_in,
                              void* d_out, int out_size, void* d_ws, size_t ws_size,
                              hipStream_t stream) {
    const float* u   = (const float*)d_in[0];
    const float* cov = (const float*)d_in[1];
    const float* z   = (const float*)d_in[2];
    float* outp = (float*)d_out;
    const int B = in_sizes[0] / CC;          // 1024

    unsigned short* zb = (unsigned short*)d_ws;                       // 258 KB
    unsigned short* Lbf = (unsigned short*)((char*)d_ws + (1 << 20)); // 29.4 MB

    zconv_kernel<<<dim3(NST), dim3(256), 0, stream>>>(z, zb);
    chol_kernel <<<dim3(B),   dim3(64),  0, stream>>>(cov, Lbf);
    pred_kernel <<<dim3(B),   dim3(256), 0, stream>>>(u, Lbf, zb, outp);
}

// Round 5
// 321.428 us; speedup vs baseline: 8.1078x; 1.2446x over previous
//
#include <hip/hip_runtime.h>

// GaussianSamplingPredict: B=1024, C=100, S=1000
//   L = cholesky(cov + 1e-6 I); t[b,s,d] = u[b,d] + sum_c z[s,c]*L[b,d,c]
//   out[b,d] = mean_s softmax_d(t[b,s,:])[d]
//
// R4: blocked Cholesky (NB=16). R3's rank-1 right-looking swept the whole
// trailing matrix once per column (100 dependent LDS read-modify-write
// passes; DS pipe is per-CU shared by 4 blocks -> 335 us). Blocked version:
// panel factor touches only 16 rows per column; trailing update is rank-16,
// touching each trailing element once per panel with 16 independent
// (pipelined) LDS reads accumulated in registers.

#define CC   100
#define SS   1000
#define EPSF 1e-6f
#define NB   16     // Cholesky panel width
#define NDT  7      // d-tiles: 7*16 = 112 >= 100
#define NCS  4      // c-steps: 4*32 = 128 >= 100
#define NST  63     // s-tiles: 63*16 = 1008 >= 1000

typedef short  s8 __attribute__((ext_vector_type(8)));   // 8 bf16 (4 VGPR)
typedef float  f4 __attribute__((ext_vector_type(4)));

__device__ inline unsigned short f2bf(float x) {          // round-nearest-even
    unsigned u = __float_as_uint(x);
    return (unsigned short)((u + 0x7fffu + ((u >> 16) & 1u)) >> 16);
}

// ---------------- K0: pack z -> bf16 A-frags ----------------
// zb frag layout: [stile][cstep][lane][j]; A-frag lane l: s = stile*16+(l&15),
// c = cstep*32 + (l>>4)*8 + j. Zero-pad s>=1000, c>=100.
__global__ __launch_bounds__(256)
void zconv_kernel(const float* __restrict__ z, unsigned short* __restrict__ zb) {
    const int stile = blockIdx.x;            // 0..62
    const int cs = threadIdx.x >> 6;
    const int l  = threadIdx.x & 63;
    const int s  = stile * 16 + (l & 15);
    const int c0 = cs * 32 + (l >> 4) * 8;
    unsigned short v[8];
    #pragma unroll
    for (int j = 0; j < 8; ++j) {
        const int c = c0 + j;
        const float x = (s < SS && c < CC) ? z[(size_t)s * CC + c] : 0.0f;
        v[j] = f2bf(x);
    }
    uint4 pk;
    pk.x = (unsigned)v[0] | ((unsigned)v[1] << 16);
    pk.y = (unsigned)v[2] | ((unsigned)v[3] << 16);
    pk.z = (unsigned)v[4] | ((unsigned)v[5] << 16);
    pk.w = (unsigned)v[6] | ((unsigned)v[7] << 16);
    reinterpret_cast<uint4*>(zb)[(stile * NCS + cs) * 64 + l] = pk;
}

// ---------------- K1: blocked Cholesky + B-frag pack ----------------
// Storage: M[x*100+y] = L[y][x] for y>=x ("row x" = column x of L).
__global__ __launch_bounds__(64)
void chol_kernel(const float* __restrict__ cov, unsigned short* __restrict__ Lb) {
    __shared__ float M[CC * CC];
    const int l  = threadIdx.x;
    const int b  = blockIdx.x;

    const float4* c4 = reinterpret_cast<const float4*>(cov + (size_t)b * CC * CC);
    for (int t = l; t < CC * CC / 4; t += 64)
        reinterpret_cast<float4*>(M)[t] = c4[t];
    __syncthreads();
    for (int d = l; d < CC; d += 64) M[d * CC + d] += EPSF;
    __syncthreads();

    for (int jb = 0; jb < CC; jb += NB) {
        const int jend = (jb + NB < CC) ? jb + NB : CC;

        // ---- panel factorization: columns jb..jend-1, rank-1 restricted
        //      to panel rows only ----
        for (int j = jb; j < jend; ++j) {
            const float val   = M[j * CC + j];     // updated Schur diag
            const float s     = sqrtf(val);
            const float dinv  = 1.0f / s;
            const float dinv2 = 1.0f / val;
            for (int k = j + 1; k < jend; ++k) {   // <= 15 serial rows
                const float t = M[j * CC + k] * dinv2;   // uniform broadcast
                for (int i = k + l; i < CC; i += 64)
                    M[k * CC + i] -= M[j * CC + i] * t;  // consecutive i
            }
            for (int i = j + 1 + l; i < CC; i += 64) M[j * CC + i] *= dinv;
            if (l == 0) M[j * CC + j] = s;
            // single-wave lockstep + compiler lgkmcnt waits give ordering
        }

        // ---- rank-16 trailing update: rows k >= jend ----
        // (runs only when panel width == NB: jb <= 80)
        for (int k = jend; k < CC; ++k) {
            float bk[NB];
            #pragma unroll
            for (int jj = 0; jj < NB; ++jj)
                bk[jj] = M[(jb + jj) * CC + k];          // uniform broadcast
            for (int i = k + l; i < CC; i += 64) {
                float acc = M[k * CC + i];
                #pragma unroll
                for (int jj = 0; jj < NB; ++jj)          // 16 independent reads
                    acc -= M[(jb + jj) * CC + i] * bk[jj];
                M[k * CC + i] = acc;
            }
        }
    }

    // pack B-frags: Lb[b][dt][cs][lane][j]; lane l: d = dt*16+(l&15),
    // c = cs*32+(l>>4)*8+j; val = L[d][c] = M[c*100+d] if c<=d<100 else 0.
    const int tx = l & 15;
    const int ty = l >> 4;
    unsigned short* outp = Lb + (size_t)b * (NDT * NCS * 64 * 8);
    for (int f = 0; f < NDT * NCS; ++f) {
        const int dt = f >> 2, cs = f & 3;
        const int d  = dt * 16 + tx;
        const int c0 = cs * 32 + ty * 8;
        unsigned short v[8];
        #pragma unroll
        for (int j = 0; j < 8; ++j) {
            const int c = c0 + j;
            float x = 0.0f;
            if (d < CC && c <= d) x = M[c * CC + d];   // c<=d implies c<100
            v[j] = f2bf(x);
        }
        uint4 pk;
        pk.x = (unsigned)v[0] | ((unsigned)v[1] << 16);
        pk.y = (unsigned)v[2] | ((unsigned)v[3] << 16);
        pk.z = (unsigned)v[4] | ((unsigned)v[5] << 16);
        pk.w = (unsigned)v[6] | ((unsigned)v[7] << 16);
        reinterpret_cast<uint4*>(outp)[f * 64 + l] = pk;
    }
}

// ---------------- K2: MFMA matmul + softmax + mean ----------------
__global__ __launch_bounds__(256, 1)
void pred_kernel(const float* __restrict__ u,
                 const unsigned short* __restrict__ Lb,
                 const unsigned short* __restrict__ zb,
                 float* __restrict__ out) {
    __shared__ float red[4 * NDT * 16];
    const int tid = threadIdx.x, b = blockIdx.x;
    const int w  = tid >> 6;
    const int l  = tid & 63;
    const int li = l & 15;
    const int hi = l >> 4;

    // persistent B-frags (L): 28 x 4 VGPR = 112 VGPR
    s8 Bf[NDT][NCS];
    const s8* Lb8 = reinterpret_cast<const s8*>(Lb + (size_t)b * (NDT * NCS * 64 * 8));
    #pragma unroll
    for (int dt = 0; dt < NDT; ++dt)
        #pragma unroll
        for (int cs = 0; cs < NCS; ++cs)
            Bf[dt][cs] = Lb8[(dt * NCS + cs) * 64 + l];

    float ureg[NDT];
    #pragma unroll
    for (int dt = 0; dt < NDT; ++dt) {
        const int d = dt * 16 + li;
        ureg[dt] = (d < CC) ? u[(size_t)b * CC + d] : 0.0f;
    }

    float meanAcc[NDT];
    #pragma unroll
    for (int dt = 0; dt < NDT; ++dt) meanAcc[dt] = 0.0f;

    const s8* zb8 = reinterpret_cast<const s8*>(zb);

    for (int st = w; st < NST; st += 4) {
        s8 Af[NCS];
        #pragma unroll
        for (int cs = 0; cs < NCS; ++cs)
            Af[cs] = zb8[(st * NCS + cs) * 64 + l];

        f4 acc[NDT];
        #pragma unroll
        for (int dt = 0; dt < NDT; ++dt) acc[dt] = (f4){0.f, 0.f, 0.f, 0.f};

        #pragma unroll
        for (int cs = 0; cs < NCS; ++cs)
            #pragma unroll
            for (int dt = 0; dt < NDT; ++dt)
                acc[dt] = __builtin_amdgcn_mfma_f32_16x16x32_bf16(
                              Af[cs], Bf[dt][cs], acc[dt], 0, 0, 0);

        // D layout: col(d_local)=li, row(s_local)=hi*4+r
        #pragma unroll
        for (int r = 0; r < 4; ++r) {
            const int s = st * 16 + hi * 4 + r;
            float tv[NDT];
            #pragma unroll
            for (int dt = 0; dt < NDT; ++dt) {
                float x = acc[dt][r] + ureg[dt];
                if (dt == NDT - 1 && li >= 4) x = -1e30f;   // pad d >= 100
                tv[dt] = x;
            }
            float m = tv[0];
            #pragma unroll
            for (int dt = 1; dt < NDT; ++dt) m = fmaxf(m, tv[dt]);
            m = fmaxf(m, __shfl_xor(m, 1));
            m = fmaxf(m, __shfl_xor(m, 2));
            m = fmaxf(m, __shfl_xor(m, 4));
            m = fmaxf(m, __shfl_xor(m, 8));
            float e[NDT], sum = 0.0f;
            #pragma unroll
            for (int dt = 0; dt < NDT; ++dt) {
                e[dt] = __expf(tv[dt] - m);
                sum += e[dt];
            }
            sum += __shfl_xor(sum, 1);
            sum += __shfl_xor(sum, 2);
            sum += __shfl_xor(sum, 4);
            sum += __shfl_xor(sum, 8);
            const float wt = (s < SS) ? 1.0f / sum : 0.0f;
            #pragma unroll
            for (int dt = 0; dt < NDT; ++dt) meanAcc[dt] += e[dt] * wt;
        }
    }

    // sum the 4 hi-groups (same d, different s-rows)
    #pragma unroll
    for (int dt = 0; dt < NDT; ++dt) {
        float v = meanAcc[dt];
        v += __shfl_xor(v, 16);
        v += __shfl_xor(v, 32);
        meanAcc[dt] = v;
    }
    if (l < 16) {
        #pragma unroll
        for (int dt = 0; dt < NDT; ++dt)
            red[(w * NDT + dt) * 16 + l] = meanAcc[dt];
    }
    __syncthreads();
    if (tid < CC) {
        const int dt = tid >> 4, li2 = tid & 15;
        const float sum = red[(0 * NDT + dt) * 16 + li2]
                        + red[(1 * NDT + dt) * 16 + li2]
                        + red[(2 * NDT + dt) * 16 + li2]
                        + red[(3 * NDT + dt) * 16 + li2];
        out[(size_t)b * CC + tid] = sum * (1.0f / (float)SS);
    }
}

extern "C" void kernel_launch(void* const* d_in, const int* in_sizes, int n_in,
                              void* d_out, int out_size, void* d_ws, size_t ws_size,
                              hipStream_t stream) {
    const float* u   = (const float*)d_in[0];
    const float* cov = (const float*)d_in[1];
    const float* z   = (const float*)d_in[2];
    float* outp = (float*)d_out;
    const int B = in_sizes[0] / CC;          // 1024

    unsigned short* zb = (unsigned short*)d_ws;                       // 258 KB
    unsigned short* Lbf = (unsigned short*)((char*)d_ws + (1 << 20)); // 29.4 MB

    zconv_kernel<<<dim3(NST), dim3(256), 0, stream>>>(z, zb);
    chol_kernel <<<dim3(B),   dim3(64),  0, stream>>>(cov, Lbf);
    pred_kernel <<<dim3(B),   dim3(256), 0, stream>>>(u, Lbf, zb, outp);
}

// Round 6
// 239.192 us; speedup vs baseline: 10.8954x; 1.3438x over previous
//
#include <hip/hip_runtime.h>

// GaussianSamplingPredict: B=1024, C=100, S=1000
//   L = cholesky(cov + 1e-6 I); t[b,s,d] = u[b,d] + sum_c z[s,c]*L[b,d,c]
//   out[b,d] = mean_s softmax_d(t[b,s,:])[d]
//
// R5: multi-wave Cholesky. R4 was 1 wave/block = 1 wave/SIMD (Occ 11.7%),
// pure LDS-latency-bound (VALUBusy 21%). Now 256 thr (4 waves)/matrix:
//  - panel factorization: wave 0 (serial dependency chain, unchanged math)
//  - rank-16 trailing update: rows round-robin across 4 waves; full-width
//    rows (i from jend) make the lane->col map row-invariant so the 16
//    panel rows are cached in registers (P0/P1) once per panel. Mirror-
//    region writes are benign (never read). Valid-region math bit-identical
//    to R4.
//  - __launch_bounds__(256,4): VGPR cap ~128 >= live ~100 (R1 lesson:
//    second arg is a hard VGPR divider; size live set against it).

#define CC   100
#define SS   1000
#define EPSF 1e-6f
#define NB   16     // Cholesky panel width
#define NDT  7      // d-tiles: 7*16 = 112 >= 100
#define NCS  4      // c-steps: 4*32 = 128 >= 100
#define NST  63     // s-tiles: 63*16 = 1008 >= 1000

typedef short  s8 __attribute__((ext_vector_type(8)));   // 8 bf16 (4 VGPR)
typedef float  f4 __attribute__((ext_vector_type(4)));

__device__ inline unsigned short f2bf(float x) {          // round-nearest-even
    unsigned u = __float_as_uint(x);
    return (unsigned short)((u + 0x7fffu + ((u >> 16) & 1u)) >> 16);
}

// ---------------- K0: pack z -> bf16 A-frags ----------------
// zb frag layout: [stile][cstep][lane][j]; A-frag lane l: s = stile*16+(l&15),
// c = cstep*32 + (l>>4)*8 + j. Zero-pad s>=1000, c>=100.
__global__ __launch_bounds__(256)
void zconv_kernel(const float* __restrict__ z, unsigned short* __restrict__ zb) {
    const int stile = blockIdx.x;            // 0..62
    const int cs = threadIdx.x >> 6;
    const int l  = threadIdx.x & 63;
    const int s  = stile * 16 + (l & 15);
    const int c0 = cs * 32 + (l >> 4) * 8;
    unsigned short v[8];
    #pragma unroll
    for (int j = 0; j < 8; ++j) {
        const int c = c0 + j;
        const float x = (s < SS && c < CC) ? z[(size_t)s * CC + c] : 0.0f;
        v[j] = f2bf(x);
    }
    uint4 pk;
    pk.x = (unsigned)v[0] | ((unsigned)v[1] << 16);
    pk.y = (unsigned)v[2] | ((unsigned)v[3] << 16);
    pk.z = (unsigned)v[4] | ((unsigned)v[5] << 16);
    pk.w = (unsigned)v[6] | ((unsigned)v[7] << 16);
    reinterpret_cast<uint4*>(zb)[(stile * NCS + cs) * 64 + l] = pk;
}

// ---------------- K1: blocked Cholesky (4 waves) + B-frag pack ----------------
// Storage: M[x*100+y] = L[y][x] for y>=x ("row x" = column x of L).
__global__ __launch_bounds__(256, 4)
void chol_kernel(const float* __restrict__ cov, unsigned short* __restrict__ Lb) {
    __shared__ float M[CC * CC];
    const int tid = threadIdx.x;
    const int w   = tid >> 6;
    const int l   = tid & 63;
    const int b   = blockIdx.x;

    const float4* c4 = reinterpret_cast<const float4*>(cov + (size_t)b * CC * CC);
    for (int t = tid; t < CC * CC / 4; t += 256)
        reinterpret_cast<float4*>(M)[t] = c4[t];
    __syncthreads();
    for (int d = tid; d < CC; d += 256) M[d * CC + d] += EPSF;
    __syncthreads();

    for (int jb = 0; jb < CC; jb += NB) {
        const int jend = (jb + NB < CC) ? jb + NB : CC;

        // ---- panel factorization: wave 0 only (serial chain) ----
        if (w == 0) {
            for (int j = jb; j < jend; ++j) {
                const float val   = M[j * CC + j];
                const float s     = sqrtf(val);
                const float dinv  = 1.0f / s;
                const float dinv2 = 1.0f / val;
                for (int k = j + 1; k < jend; ++k) {
                    const float t = M[j * CC + k] * dinv2;   // uniform bcast
                    for (int i = k + l; i < CC; i += 64)
                        M[k * CC + i] -= M[j * CC + i] * t;  // consecutive i
                }
                for (int i = j + 1 + l; i < CC; i += 64) M[j * CC + i] *= dinv;
                if (l == 0) M[j * CC + j] = s;
                // single-wave lockstep: compiler lgkmcnt waits give ordering
            }
        }
        __syncthreads();

        // ---- rank-16 trailing update, rows split across 4 waves ----
        if (jend < CC) {
            // cache finalized panel rows for this lane's two columns
            const int i0 = jend + l;
            const int i1 = i0 + 64;
            float P0[NB], P1[NB];
            #pragma unroll
            for (int jj = 0; jj < NB; ++jj) {
                P0[jj] = (i0 < CC) ? M[(jb + jj) * CC + i0] : 0.0f;
                P1[jj] = (i1 < CC) ? M[(jb + jj) * CC + i1] : 0.0f;
            }
            for (int k = jend + w; k < CC; k += 4) {
                float bk[NB];
                #pragma unroll
                for (int jj = 0; jj < NB; ++jj)
                    bk[jj] = M[(jb + jj) * CC + k];          // uniform bcast
                if (i0 < CC) {
                    float acc = M[k * CC + i0];
                    #pragma unroll
                    for (int jj = 0; jj < NB; ++jj) acc -= P0[jj] * bk[jj];
                    M[k * CC + i0] = acc;
                }
                if (i1 < CC) {
                    float acc = M[k * CC + i1];
                    #pragma unroll
                    for (int jj = 0; jj < NB; ++jj) acc -= P1[jj] * bk[jj];
                    M[k * CC + i1] = acc;
                }
            }
        }
        __syncthreads();
    }

    // pack B-frags (28 frags over 4 waves): Lb[b][dt][cs][lane][j];
    // lane l: d = dt*16+(l&15), c = cs*32+(l>>4)*8+j;
    // val = L[d][c] = M[c*100+d] if c<=d<100 else 0.
    const int tx = l & 15;
    const int ty = l >> 4;
    unsigned short* outp = Lb + (size_t)b * (NDT * NCS * 64 * 8);
    for (int f = w; f < NDT * NCS; f += 4) {
        const int dt = f >> 2, cs = f & 3;
        const int d  = dt * 16 + tx;
        const int c0 = cs * 32 + ty * 8;
        unsigned short v[8];
        #pragma unroll
        for (int j = 0; j < 8; ++j) {
            const int c = c0 + j;
            float x = 0.0f;
            if (d < CC && c <= d) x = M[c * CC + d];   // c<=d implies c<100
            v[j] = f2bf(x);
        }
        uint4 pk;
        pk.x = (unsigned)v[0] | ((unsigned)v[1] << 16);
        pk.y = (unsigned)v[2] | ((unsigned)v[3] << 16);
        pk.z = (unsigned)v[4] | ((unsigned)v[5] << 16);
        pk.w = (unsigned)v[6] | ((unsigned)v[7] << 16);
        reinterpret_cast<uint4*>(outp)[f * 64 + l] = pk;
    }
}

// ---------------- K2: MFMA matmul + softmax + mean ----------------
__global__ __launch_bounds__(256, 1)
void pred_kernel(const float* __restrict__ u,
                 const unsigned short* __restrict__ Lb,
                 const unsigned short* __restrict__ zb,
                 float* __restrict__ out) {
    __shared__ float red[4 * NDT * 16];
    const int tid = threadIdx.x, b = blockIdx.x;
    const int w  = tid >> 6;
    const int l  = tid & 63;
    const int li = l & 15;
    const int hi = l >> 4;

    // persistent B-frags (L): 28 x 4 VGPR = 112 VGPR
    s8 Bf[NDT][NCS];
    const s8* Lb8 = reinterpret_cast<const s8*>(Lb + (size_t)b * (NDT * NCS * 64 * 8));
    #pragma unroll
    for (int dt = 0; dt < NDT; ++dt)
        #pragma unroll
        for (int cs = 0; cs < NCS; ++cs)
            Bf[dt][cs] = Lb8[(dt * NCS + cs) * 64 + l];

    float ureg[NDT];
    #pragma unroll
    for (int dt = 0; dt < NDT; ++dt) {
        const int d = dt * 16 + li;
        ureg[dt] = (d < CC) ? u[(size_t)b * CC + d] : 0.0f;
    }

    float meanAcc[NDT];
    #pragma unroll
    for (int dt = 0; dt < NDT; ++dt) meanAcc[dt] = 0.0f;

    const s8* zb8 = reinterpret_cast<const s8*>(zb);

    for (int st = w; st < NST; st += 4) {
        s8 Af[NCS];
        #pragma unroll
        for (int cs = 0; cs < NCS; ++cs)
            Af[cs] = zb8[(st * NCS + cs) * 64 + l];

        f4 acc[NDT];
        #pragma unroll
        for (int dt = 0; dt < NDT; ++dt) acc[dt] = (f4){0.f, 0.f, 0.f, 0.f};

        #pragma unroll
        for (int cs = 0; cs < NCS; ++cs)
            #pragma unroll
            for (int dt = 0; dt < NDT; ++dt)
                acc[dt] = __builtin_amdgcn_mfma_f32_16x16x32_bf16(
                              Af[cs], Bf[dt][cs], acc[dt], 0, 0, 0);

        // D layout: col(d_local)=li, row(s_local)=hi*4+r
        #pragma unroll
        for (int r = 0; r < 4; ++r) {
            const int s = st * 16 + hi * 4 + r;
            float tv[NDT];
            #pragma unroll
            for (int dt = 0; dt < NDT; ++dt) {
                float x = acc[dt][r] + ureg[dt];
                if (dt == NDT - 1 && li >= 4) x = -1e30f;   // pad d >= 100
                tv[dt] = x;
            }
            float m = tv[0];
            #pragma unroll
            for (int dt = 1; dt < NDT; ++dt) m = fmaxf(m, tv[dt]);
            m = fmaxf(m, __shfl_xor(m, 1));
            m = fmaxf(m, __shfl_xor(m, 2));
            m = fmaxf(m, __shfl_xor(m, 4));
            m = fmaxf(m, __shfl_xor(m, 8));
            float e[NDT], sum = 0.0f;
            #pragma unroll
            for (int dt = 0; dt < NDT; ++dt) {
                e[dt] = __expf(tv[dt] - m);
                sum += e[dt];
            }
            sum += __shfl_xor(sum, 1);
            sum += __shfl_xor(sum, 2);
            sum += __shfl_xor(sum, 4);
            sum += __shfl_xor(sum, 8);
            const float wt = (s < SS) ? 1.0f / sum : 0.0f;
            #pragma unroll
            for (int dt = 0; dt < NDT; ++dt) meanAcc[dt] += e[dt] * wt;
        }
    }

    // sum the 4 hi-groups (same d, different s-rows)
    #pragma unroll
    for (int dt = 0; dt < NDT; ++dt) {
        float v = meanAcc[dt];
        v += __shfl_xor(v, 16);
        v += __shfl_xor(v, 32);
        meanAcc[dt] = v;
    }
    if (l < 16) {
        #pragma unroll
        for (int dt = 0; dt < NDT; ++dt)
            red[(w * NDT + dt) * 16 + l] = meanAcc[dt];
    }
    __syncthreads();
    if (tid < CC) {
        const int dt = tid >> 4, li2 = tid & 15;
        const float sum = red[(0 * NDT + dt) * 16 + li2]
                        + red[(1 * NDT + dt) * 16 + li2]
                        + red[(2 * NDT + dt) * 16 + li2]
                        + red[(3 * NDT + dt) * 16 + li2];
        out[(size_t)b * CC + tid] = sum * (1.0f / (float)SS);
    }
}

extern "C" void kernel_launch(void* const* d_in, const int* in_sizes, int n_in,
                              void* d_out, int out_size, void* d_ws, size_t ws_size,
                              hipStream_t stream) {
    const float* u   = (const float*)d_in[0];
    const float* cov = (const float*)d_in[1];
    const float* z   = (const float*)d_in[2];
    float* outp = (float*)d_out;
    const int B = in_sizes[0] / CC;          // 1024

    unsigned short* zb = (unsigned short*)d_ws;                       // 258 KB
    unsigned short* Lbf = (unsigned short*)((char*)d_ws + (1 << 20)); // 29.4 MB

    zconv_kernel<<<dim3(NST), dim3(256), 0, stream>>>(z, zb);
    chol_kernel <<<dim3(B),   dim3(256), 0, stream>>>(cov, Lbf);
    pred_kernel <<<dim3(B),   dim3(256), 0, stream>>>(u, Lbf, zb, outp);
}

// Round 7
// 139.785 us; speedup vs baseline: 18.6436x; 1.7111x over previous
//
#include <hip/hip_runtime.h>

// GaussianSamplingPredict: B=1024, C=100, S=1000
//   L = cholesky(cov + 1e-6 I); t[b,s,d] = u[b,d] + sum_c z[s,c]*L[b,d,c]
//   out[b,d] = mean_s softmax_d(t[b,s,:])[d]
//
// R6: register-resident panel factorization. R5's panel did dependent LDS
// read-modify-write chains (~120cy DS latency each) per column = the ~100 us
// residual. Now the 16x100 panel lives in wave-0 VGPRs (lane l owns cols
// l, l+64; 32 VGPR), factored with __shfl broadcasts + VALU FMA only; LDS
// touched once before (load) and once after (store) per panel. All register
// indices compile-time via template<int NPAN> (runtime-indexed arrays go to
// scratch). rsqrtf (v_rsq) replaces sqrt+div chains - drift ~1e-7, invisible
// under the bf16 L pack. Trailing update: R5 structure + unroll 2.

#define CC   100
#define SS   1000
#define EPSF 1e-6f
#define NB   16     // Cholesky panel width
#define NDT  7      // d-tiles: 7*16 = 112 >= 100
#define NCS  4      // c-steps: 4*32 = 128 >= 100
#define NST  63     // s-tiles: 63*16 = 1008 >= 1000

typedef short  s8 __attribute__((ext_vector_type(8)));   // 8 bf16 (4 VGPR)
typedef float  f4 __attribute__((ext_vector_type(4)));

__device__ inline unsigned short f2bf(float x) {          // round-nearest-even
    unsigned u = __float_as_uint(x);
    return (unsigned short)((u + 0x7fffu + ((u >> 16) & 1u)) >> 16);
}

// ---------------- K0: pack z -> bf16 A-frags ----------------
__global__ __launch_bounds__(256)
void zconv_kernel(const float* __restrict__ z, unsigned short* __restrict__ zb) {
    const int stile = blockIdx.x;            // 0..62
    const int cs = threadIdx.x >> 6;
    const int l  = threadIdx.x & 63;
    const int s  = stile * 16 + (l & 15);
    const int c0 = cs * 32 + (l >> 4) * 8;
    unsigned short v[8];
    #pragma unroll
    for (int j = 0; j < 8; ++j) {
        const int c = c0 + j;
        const float x = (s < SS && c < CC) ? z[(size_t)s * CC + c] : 0.0f;
        v[j] = f2bf(x);
    }
    uint4 pk;
    pk.x = (unsigned)v[0] | ((unsigned)v[1] << 16);
    pk.y = (unsigned)v[2] | ((unsigned)v[3] << 16);
    pk.z = (unsigned)v[4] | ((unsigned)v[5] << 16);
    pk.w = (unsigned)v[6] | ((unsigned)v[7] << 16);
    reinterpret_cast<uint4*>(zb)[(stile * NCS + cs) * 64 + l] = pk;
}

// Register-resident panel factorization for rows jb..jb+NPAN-1 (wave 0 only).
// Lane l holds cols l and l+64 of each panel row. Math is the same
// right-looking rank-1 sequence as before (raw row, t = row[k]/diag).
template<int NPAN>
__device__ inline void panel_factor(float* __restrict__ M, int jb, int l) {
    float P0r[NPAN], P1r[NPAN];
    const int i1 = l + 64;
    #pragma unroll
    for (int jj = 0; jj < NPAN; ++jj) {
        P0r[jj] = M[(jb + jj) * CC + l];
        P1r[jj] = (i1 < CC) ? M[(jb + jj) * CC + i1] : 0.0f;
    }
    #pragma unroll
    for (int jj = 0; jj < NPAN; ++jj) {
        const int j = jb + jj;
        const float dsrc  = (j & 64) ? P1r[jj] : P0r[jj];
        const float val   = __shfl(dsrc, j & 63);
        const float dinv  = rsqrtf(val);
        const float s     = val * dinv;
        const float dinv2 = dinv * dinv;
        #pragma unroll
        for (int kk = jj + 1; kk < NPAN; ++kk) {
            const int k = jb + kk;
            const float tsrc = (k & 64) ? P1r[jj] : P0r[jj];
            const float t = __shfl(tsrc, k & 63) * dinv2;
            P0r[kk] -= P0r[jj] * t;
            P1r[kk] -= P1r[jj] * t;
        }
        // finalize row jj: col > j scaled, col == j = s, col < j untouched
        P0r[jj] = (l == j) ? s : ((l > j) ? P0r[jj] * dinv : P0r[jj]);
        P1r[jj] = (i1 == j) ? s : ((i1 > j) ? P1r[jj] * dinv : P1r[jj]);
    }
    #pragma unroll
    for (int jj = 0; jj < NPAN; ++jj) {
        M[(jb + jj) * CC + l] = P0r[jj];
        if (i1 < CC) M[(jb + jj) * CC + i1] = P1r[jj];
    }
}

// ---------------- K1: blocked Cholesky (4 waves) + B-frag pack ----------------
// Storage: M[x*100+y] = L[y][x] for y>=x ("row x" = column x of L).
__global__ __launch_bounds__(256, 4)
void chol_kernel(const float* __restrict__ cov, unsigned short* __restrict__ Lb) {
    __shared__ float M[CC * CC];
    const int tid = threadIdx.x;
    const int w   = tid >> 6;
    const int l   = tid & 63;
    const int b   = blockIdx.x;

    const float4* c4 = reinterpret_cast<const float4*>(cov + (size_t)b * CC * CC);
    for (int t = tid; t < CC * CC / 4; t += 256)
        reinterpret_cast<float4*>(M)[t] = c4[t];
    __syncthreads();
    for (int d = tid; d < CC; d += 256) M[d * CC + d] += EPSF;
    __syncthreads();

    for (int jb = 0; jb < CC; jb += NB) {
        const int jend = (jb + NB < CC) ? jb + NB : CC;

        // ---- panel factorization in wave-0 registers ----
        if (w == 0) {
            if (jend - jb == NB) panel_factor<NB>(M, jb, l);
            else                 panel_factor<CC - (CC / NB) * NB>(M, jb, l); // 4
        }
        __syncthreads();

        // ---- rank-16 trailing update, rows split across 4 waves ----
        if (jend < CC) {
            // cache finalized panel rows for this lane's two columns
            const int i0 = jend + l;
            const int i1 = i0 + 64;
            float P0[NB], P1[NB];
            #pragma unroll
            for (int jj = 0; jj < NB; ++jj) {
                P0[jj] = (i0 < CC) ? M[(jb + jj) * CC + i0] : 0.0f;
                P1[jj] = (i1 < CC) ? M[(jb + jj) * CC + i1] : 0.0f;
            }
            #pragma unroll 2
            for (int k = jend + w; k < CC; k += 4) {
                float bk[NB];
                #pragma unroll
                for (int jj = 0; jj < NB; ++jj)
                    bk[jj] = M[(jb + jj) * CC + k];          // uniform bcast
                if (i0 < CC) {
                    float acc = M[k * CC + i0];
                    #pragma unroll
                    for (int jj = 0; jj < NB; ++jj) acc -= P0[jj] * bk[jj];
                    M[k * CC + i0] = acc;
                }
                if (i1 < CC) {
                    float acc = M[k * CC + i1];
                    #pragma unroll
                    for (int jj = 0; jj < NB; ++jj) acc -= P1[jj] * bk[jj];
                    M[k * CC + i1] = acc;
                }
            }
        }
        __syncthreads();
    }

    // pack B-frags (28 frags over 4 waves): Lb[b][dt][cs][lane][j];
    // lane l: d = dt*16+(l&15), c = cs*32+(l>>4)*8+j;
    // val = L[d][c] = M[c*100+d] if c<=d<100 else 0.
    const int tx = l & 15;
    const int ty = l >> 4;
    unsigned short* outp = Lb + (size_t)b * (NDT * NCS * 64 * 8);
    for (int f = w; f < NDT * NCS; f += 4) {
        const int dt = f >> 2, cs = f & 3;
        const int d  = dt * 16 + tx;
        const int c0 = cs * 32 + ty * 8;
        unsigned short v[8];
        #pragma unroll
        for (int j = 0; j < 8; ++j) {
            const int c = c0 + j;
            float x = 0.0f;
            if (d < CC && c <= d) x = M[c * CC + d];   // c<=d implies c<100
            v[j] = f2bf(x);
        }
        uint4 pk;
        pk.x = (unsigned)v[0] | ((unsigned)v[1] << 16);
        pk.y = (unsigned)v[2] | ((unsigned)v[3] << 16);
        pk.z = (unsigned)v[4] | ((unsigned)v[5] << 16);
        pk.w = (unsigned)v[6] | ((unsigned)v[7] << 16);
        reinterpret_cast<uint4*>(outp)[f * 64 + l] = pk;
    }
}

// ---------------- K2: MFMA matmul + softmax + mean ----------------
__global__ __launch_bounds__(256, 1)
void pred_kernel(const float* __restrict__ u,
                 const unsigned short* __restrict__ Lb,
                 const unsigned short* __restrict__ zb,
                 float* __restrict__ out) {
    __shared__ float red[4 * NDT * 16];
    const int tid = threadIdx.x, b = blockIdx.x;
    const int w  = tid >> 6;
    const int l  = tid & 63;
    const int li = l & 15;
    const int hi = l >> 4;

    // persistent B-frags (L): 28 x 4 VGPR = 112 VGPR
    s8 Bf[NDT][NCS];
    const s8* Lb8 = reinterpret_cast<const s8*>(Lb + (size_t)b * (NDT * NCS * 64 * 8));
    #pragma unroll
    for (int dt = 0; dt < NDT; ++dt)
        #pragma unroll
        for (int cs = 0; cs < NCS; ++cs)
            Bf[dt][cs] = Lb8[(dt * NCS + cs) * 64 + l];

    float ureg[NDT];
    #pragma unroll
    for (int dt = 0; dt < NDT; ++dt) {
        const int d = dt * 16 + li;
        ureg[dt] = (d < CC) ? u[(size_t)b * CC + d] : 0.0f;
    }

    float meanAcc[NDT];
    #pragma unroll
    for (int dt = 0; dt < NDT; ++dt) meanAcc[dt] = 0.0f;

    const s8* zb8 = reinterpret_cast<const s8*>(zb);

    for (int st = w; st < NST; st += 4) {
        s8 Af[NCS];
        #pragma unroll
        for (int cs = 0; cs < NCS; ++cs)
            Af[cs] = zb8[(st * NCS + cs) * 64 + l];

        f4 acc[NDT];
        #pragma unroll
        for (int dt = 0; dt < NDT; ++dt) acc[dt] = (f4){0.f, 0.f, 0.f, 0.f};

        #pragma unroll
        for (int cs = 0; cs < NCS; ++cs)
            #pragma unroll
            for (int dt = 0; dt < NDT; ++dt)
                acc[dt] = __builtin_amdgcn_mfma_f32_16x16x32_bf16(
                              Af[cs], Bf[dt][cs], acc[dt], 0, 0, 0);

        // D layout: col(d_local)=li, row(s_local)=hi*4+r
        #pragma unroll
        for (int r = 0; r < 4; ++r) {
            const int s = st * 16 + hi * 4 + r;
            float tv[NDT];
            #pragma unroll
            for (int dt = 0; dt < NDT; ++dt) {
                float x = acc[dt][r] + ureg[dt];
                if (dt == NDT - 1 && li >= 4) x = -1e30f;   // pad d >= 100
                tv[dt] = x;
            }
            float m = tv[0];
            #pragma unroll
            for (int dt = 1; dt < NDT; ++dt) m = fmaxf(m, tv[dt]);
            m = fmaxf(m, __shfl_xor(m, 1));
            m = fmaxf(m, __shfl_xor(m, 2));
            m = fmaxf(m, __shfl_xor(m, 4));
            m = fmaxf(m, __shfl_xor(m, 8));
            float e[NDT], sum = 0.0f;
            #pragma unroll
            for (int dt = 0; dt < NDT; ++dt) {
                e[dt] = __expf(tv[dt] - m);
                sum += e[dt];
            }
            sum += __shfl_xor(sum, 1);
            sum += __shfl_xor(sum, 2);
            sum += __shfl_xor(sum, 4);
            sum += __shfl_xor(sum, 8);
            const float wt = (s < SS) ? 1.0f / sum : 0.0f;
            #pragma unroll
            for (int dt = 0; dt < NDT; ++dt) meanAcc[dt] += e[dt] * wt;
        }
    }

    // sum the 4 hi-groups (same d, different s-rows)
    #pragma unroll
    for (int dt = 0; dt < NDT; ++dt) {
        float v = meanAcc[dt];
        v += __shfl_xor(v, 16);
        v += __shfl_xor(v, 32);
        meanAcc[dt] = v;
    }
    if (l < 16) {
        #pragma unroll
        for (int dt = 0; dt < NDT; ++dt)
            red[(w * NDT + dt) * 16 + l] = meanAcc[dt];
    }
    __syncthreads();
    if (tid < CC) {
        const int dt = tid >> 4, li2 = tid & 15;
        const float sum = red[(0 * NDT + dt) * 16 + li2]
                        + red[(1 * NDT + dt) * 16 + li2]
                        + red[(2 * NDT + dt) * 16 + li2]
                        + red[(3 * NDT + dt) * 16 + li2];
        out[(size_t)b * CC + tid] = sum * (1.0f / (float)SS);
    }
}

extern "C" void kernel_launch(void* const* d_in, const int* in_sizes, int n_in,
                              void* d_out, int out_size, void* d_ws, size_t ws_size,
                              hipStream_t stream) {
    const float* u   = (const float*)d_in[0];
    const float* cov = (const float*)d_in[1];
    const float* z   = (const float*)d_in[2];
    float* outp = (float*)d_out;
    const int B = in_sizes[0] / CC;          // 1024

    unsigned short* zb = (unsigned short*)d_ws;                       // 258 KB
    unsigned short* Lbf = (unsigned short*)((char*)d_ws + (1 << 20)); // 29.4 MB

    zconv_kernel<<<dim3(NST), dim3(256), 0, stream>>>(z, zb);
    chol_kernel <<<dim3(B),   dim3(256), 0, stream>>>(cov, Lbf);
    pred_kernel <<<dim3(B),   dim3(256), 0, stream>>>(u, Lbf, zb, outp);
}

// Round 8
// 114.731 us; speedup vs baseline: 22.7148x; 1.2184x over previous
//
#include <hip/hip_runtime.h>

// GaussianSamplingPredict: B=1024, C=100, S=1000
//   L = cholesky(cov + 1e-6 I); t[b,s,d] = u[b,d] + sum_c z[s,c]*L[b,d,c]
//   out[b,d] = mean_s softmax_d(t[b,s,:])[d]
//
// R7: epilogue-free pred. R6's pred was VALU/DS-chain-bound in the softmax
// epilogue (MfmaUtil 14%, 32 dependent ds_swizzles per tile).
//  (a) swapped MFMA operands: mfma(Lfrag, zfrag) -> D[row=d][col=s]; each
//      lane owns one s with 28 d-values in-register -> reduce = 27 adds +
//      xor16 + xor32 only.
//  (b) u folded into the matmul via the c-padding: z[:,100]=z[:,101]=1,
//      L[d][100]=u_hi, L[d][101]=u_lo (2-piece bf16). Pad rows d>=100 get
//      -1e30 at c=100 -> exp->0, no masking needed.
//  (c) base-2 softmax, no max-subtract (|logit|<=~11, fp32-safe): L,u
//      pre-scaled by log2(e) at pack time; epilogue exp = bare v_exp_f32.

#define CC    100
#define SS    1000
#define EPSF  1e-6f
#define NB    16     // Cholesky panel width
#define NDT   7      // d-tiles: 7*16 = 112 >= 100
#define NCS   4      // c-steps: 4*32 = 128 >= 102
#define NST   63     // s-tiles: 63*16 = 1008 >= 1000
#define LOG2E 1.44269504088896340736f

typedef short  s8 __attribute__((ext_vector_type(8)));   // 8 bf16 (4 VGPR)
typedef float  f4 __attribute__((ext_vector_type(4)));

__device__ inline unsigned short f2bf(float x) {          // round-nearest-even
    unsigned u = __float_as_uint(x);
    return (unsigned short)((u + 0x7fffu + ((u >> 16) & 1u)) >> 16);
}
__device__ inline float bf2f(unsigned short h) {
    return __uint_as_float(((unsigned)h) << 16);
}

// ---------------- K0: pack z -> bf16 frags (+ ones at c=100,101) ----------------
// frag layout: [stile][cstep][lane][j]; lane l: s = stile*16+(l&15),
// c = cstep*32 + (l>>4)*8 + j.
__global__ __launch_bounds__(256)
void zconv_kernel(const float* __restrict__ z, unsigned short* __restrict__ zb) {
    const int stile = blockIdx.x;            // 0..62
    const int cs = threadIdx.x >> 6;
    const int l  = threadIdx.x & 63;
    const int s  = stile * 16 + (l & 15);
    const int c0 = cs * 32 + (l >> 4) * 8;
    unsigned short v[8];
    #pragma unroll
    for (int j = 0; j < 8; ++j) {
        const int c = c0 + j;
        float x = 0.0f;
        if (c < CC)      x = (s < SS) ? z[(size_t)s * CC + c] : 0.0f;
        else if (c <= CC + 1) x = 1.0f;          // u_hi / u_lo slots
        v[j] = f2bf(x);
    }
    uint4 pk;
    pk.x = (unsigned)v[0] | ((unsigned)v[1] << 16);
    pk.y = (unsigned)v[2] | ((unsigned)v[3] << 16);
    pk.z = (unsigned)v[4] | ((unsigned)v[5] << 16);
    pk.w = (unsigned)v[6] | ((unsigned)v[7] << 16);
    reinterpret_cast<uint4*>(zb)[(stile * NCS + cs) * 64 + l] = pk;
}

// Register-resident panel factorization (wave 0 only). Lane l holds cols
// l and l+64 of each panel row.
template<int NPAN>
__device__ inline void panel_factor(float* __restrict__ M, int jb, int l) {
    float P0r[NPAN], P1r[NPAN];
    const int i1 = l + 64;
    #pragma unroll
    for (int jj = 0; jj < NPAN; ++jj) {
        P0r[jj] = M[(jb + jj) * CC + l];
        P1r[jj] = (i1 < CC) ? M[(jb + jj) * CC + i1] : 0.0f;
    }
    #pragma unroll
    for (int jj = 0; jj < NPAN; ++jj) {
        const int j = jb + jj;
        const float dsrc  = (j & 64) ? P1r[jj] : P0r[jj];
        const float val   = __shfl(dsrc, j & 63);
        const float dinv  = rsqrtf(val);
        const float s     = val * dinv;
        const float dinv2 = dinv * dinv;
        #pragma unroll
        for (int kk = jj + 1; kk < NPAN; ++kk) {
            const int k = jb + kk;
            const float tsrc = (k & 64) ? P1r[jj] : P0r[jj];
            const float t = __shfl(tsrc, k & 63) * dinv2;
            P0r[kk] -= P0r[jj] * t;
            P1r[kk] -= P1r[jj] * t;
        }
        P0r[jj] = (l == j) ? s : ((l > j) ? P0r[jj] * dinv : P0r[jj]);
        P1r[jj] = (i1 == j) ? s : ((i1 > j) ? P1r[jj] * dinv : P1r[jj]);
    }
    #pragma unroll
    for (int jj = 0; jj < NPAN; ++jj) {
        M[(jb + jj) * CC + l] = P0r[jj];
        if (i1 < CC) M[(jb + jj) * CC + i1] = P1r[jj];
    }
}

// ---------------- K1: blocked Cholesky (4 waves) + frag pack ----------------
// Storage: M[x*100+y] = L[y][x] for y>=x. Pack applies LOG2E scaling and
// appends u_hi/u_lo columns (c=100/101) and -1e30 pad sentinels.
__global__ __launch_bounds__(256, 4)
void chol_kernel(const float* __restrict__ cov, const float* __restrict__ u,
                 unsigned short* __restrict__ Lb) {
    __shared__ float M[CC * CC];
    const int tid = threadIdx.x;
    const int w   = tid >> 6;
    const int l   = tid & 63;
    const int b   = blockIdx.x;

    const float4* c4 = reinterpret_cast<const float4*>(cov + (size_t)b * CC * CC);
    for (int t = tid; t < CC * CC / 4; t += 256)
        reinterpret_cast<float4*>(M)[t] = c4[t];
    __syncthreads();
    for (int d = tid; d < CC; d += 256) M[d * CC + d] += EPSF;
    __syncthreads();

    for (int jb = 0; jb < CC; jb += NB) {
        const int jend = (jb + NB < CC) ? jb + NB : CC;

        if (w == 0) {
            if (jend - jb == NB) panel_factor<NB>(M, jb, l);
            else                 panel_factor<CC - (CC / NB) * NB>(M, jb, l); // 4
        }
        __syncthreads();

        if (jend < CC) {
            const int i0 = jend + l;
            const int i1 = i0 + 64;
            float P0[NB], P1[NB];
            #pragma unroll
            for (int jj = 0; jj < NB; ++jj) {
                P0[jj] = (i0 < CC) ? M[(jb + jj) * CC + i0] : 0.0f;
                P1[jj] = (i1 < CC) ? M[(jb + jj) * CC + i1] : 0.0f;
            }
            #pragma unroll 2
            for (int k = jend + w; k < CC; k += 4) {
                float bk[NB];
                #pragma unroll
                for (int jj = 0; jj < NB; ++jj)
                    bk[jj] = M[(jb + jj) * CC + k];          // uniform bcast
                if (i0 < CC) {
                    float acc = M[k * CC + i0];
                    #pragma unroll
                    for (int jj = 0; jj < NB; ++jj) acc -= P0[jj] * bk[jj];
                    M[k * CC + i0] = acc;
                }
                if (i1 < CC) {
                    float acc = M[k * CC + i1];
                    #pragma unroll
                    for (int jj = 0; jj < NB; ++jj) acc -= P1[jj] * bk[jj];
                    M[k * CC + i1] = acc;
                }
            }
        }
        __syncthreads();
    }

    // pack frags (28 over 4 waves): lane l: d = dt*16+(l&15),
    // c = cs*32+(l>>4)*8+j.
    //   c<100:  L[d][c]*LOG2E (0 above diagonal / pad rows)
    //   c==100: bf16(u[d]*LOG2E), or -1e30 for pad rows d>=100
    //   c==101: residual u*LOG2E - u_hi (0 for pad rows)
    const int tx = l & 15;
    const int ty = l >> 4;
    unsigned short* outp = Lb + (size_t)b * (NDT * NCS * 64 * 8);
    for (int f = w; f < NDT * NCS; f += 4) {
        const int dt = f >> 2, cs = f & 3;
        const int d  = dt * 16 + tx;
        const int c0 = cs * 32 + ty * 8;
        unsigned short v[8];
        #pragma unroll
        for (int j = 0; j < 8; ++j) {
            const int c = c0 + j;
            float x = 0.0f;
            if (c < CC) {
                if (d < CC && c <= d) x = M[c * CC + d] * LOG2E;
            } else if (c == CC) {
                if (d < CC) x = bf2f(f2bf(u[(size_t)b * CC + d] * LOG2E));
                else        x = -1e30f;              // pad row kill switch
            } else if (c == CC + 1) {
                if (d < CC) {
                    const float t = u[(size_t)b * CC + d] * LOG2E;
                    x = t - bf2f(f2bf(t));           // residual
                }
            }
            v[j] = f2bf(x);
        }
        uint4 pk;
        pk.x = (unsigned)v[0] | ((unsigned)v[1] << 16);
        pk.y = (unsigned)v[2] | ((unsigned)v[3] << 16);
        pk.z = (unsigned)v[4] | ((unsigned)v[5] << 16);
        pk.w = (unsigned)v[6] | ((unsigned)v[7] << 16);
        reinterpret_cast<uint4*>(outp)[f * 64 + l] = pk;
    }
}

// ---------------- K2: MFMA matmul + base-2 softmax + mean ----------------
__global__ __launch_bounds__(256, 1)
void pred_kernel(const unsigned short* __restrict__ Lb,
                 const unsigned short* __restrict__ zb,
                 float* __restrict__ out) {
    __shared__ float red[4 * NDT * 16];
    const int tid = threadIdx.x, b = blockIdx.x;
    const int w  = tid >> 6;
    const int l  = tid & 63;
    const int li = l & 15;
    const int hi = l >> 4;

    // persistent L-frags: 28 x 4 VGPR = 112 VGPR
    s8 Bf[NDT][NCS];
    const s8* Lb8 = reinterpret_cast<const s8*>(Lb + (size_t)b * (NDT * NCS * 64 * 8));
    #pragma unroll
    for (int dt = 0; dt < NDT; ++dt)
        #pragma unroll
        for (int cs = 0; cs < NCS; ++cs)
            Bf[dt][cs] = Lb8[(dt * NCS + cs) * 64 + l];

    float meanAcc[NDT][4];
    #pragma unroll
    for (int dt = 0; dt < NDT; ++dt)
        #pragma unroll
        for (int r = 0; r < 4; ++r) meanAcc[dt][r] = 0.0f;

    const s8* zb8 = reinterpret_cast<const s8*>(zb);

    for (int st = w; st < NST; st += 4) {
        s8 Af[NCS];
        #pragma unroll
        for (int cs = 0; cs < NCS; ++cs)
            Af[cs] = zb8[(st * NCS + cs) * 64 + l];

        f4 acc[NDT];
        #pragma unroll
        for (int dt = 0; dt < NDT; ++dt) acc[dt] = (f4){0.f, 0.f, 0.f, 0.f};

        // swapped operands: D[row=d][col=s]; lane: d = dt*16+hi*4+r, s = st*16+li
        #pragma unroll
        for (int cs = 0; cs < NCS; ++cs)
            #pragma unroll
            for (int dt = 0; dt < NDT; ++dt)
                acc[dt] = __builtin_amdgcn_mfma_f32_16x16x32_bf16(
                              Bf[dt][cs], Af[cs], acc[dt], 0, 0, 0);

        // base-2 softmax over d for this lane's s; no max-subtract.
        float e[NDT][4];
        float rs = 0.0f;
        #pragma unroll
        for (int dt = 0; dt < NDT; ++dt)
            #pragma unroll
            for (int r = 0; r < 4; ++r) {
                const float ev = __builtin_amdgcn_exp2f(acc[dt][r]);
                e[dt][r] = ev;
                rs += ev;
            }
        rs += __shfl_xor(rs, 16);
        rs += __shfl_xor(rs, 32);
        const float wgt = (st * 16 + li < SS) ? __builtin_amdgcn_rcpf(rs) : 0.0f;
        #pragma unroll
        for (int dt = 0; dt < NDT; ++dt)
            #pragma unroll
            for (int r = 0; r < 4; ++r) meanAcc[dt][r] += e[dt][r] * wgt;
    }

    // reduce across the 16 li lanes (same d, different s)
    #pragma unroll
    for (int dt = 0; dt < NDT; ++dt)
        #pragma unroll
        for (int r = 0; r < 4; ++r) {
            float v = meanAcc[dt][r];
            v += __shfl_xor(v, 1);
            v += __shfl_xor(v, 2);
            v += __shfl_xor(v, 4);
            v += __shfl_xor(v, 8);
            if (li == 0) red[w * (NDT * 16) + dt * 16 + hi * 4 + r] = v;
        }
    __syncthreads();
    if (tid < CC) {
        const float sum = red[tid] + red[NDT * 16 + tid] +
                          red[2 * NDT * 16 + tid] + red[3 * NDT * 16 + tid];
        out[(size_t)b * CC + tid] = sum * (1.0f / (float)SS);
    }
}

extern "C" void kernel_launch(void* const* d_in, const int* in_sizes, int n_in,
                              void* d_out, int out_size, void* d_ws, size_t ws_size,
                              hipStream_t stream) {
    const float* u   = (const float*)d_in[0];
    const float* cov = (const float*)d_in[1];
    const float* z   = (const float*)d_in[2];
    float* outp = (float*)d_out;
    const int B = in_sizes[0] / CC;          // 1024

    unsigned short* zb = (unsigned short*)d_ws;                       // 258 KB
    unsigned short* Lbf = (unsigned short*)((char*)d_ws + (1 << 20)); // 29.4 MB

    zconv_kernel<<<dim3(NST), dim3(256), 0, stream>>>(z, zb);
    chol_kernel <<<dim3(B),   dim3(256), 0, stream>>>(cov, u, Lbf);
    pred_kernel <<<dim3(B),   dim3(256), 0, stream>>>(Lbf, zb, outp);
}